// Round 1
// 194.377 us; speedup vs baseline: 1.0278x; 1.0278x over previous
//
#include <hip/hip_runtime.h>
#include <hip/hip_bf16.h>

#define IN_F   64
#define OUT_F  64
#define N_RELS 32
#define N_BAS  30
#define KROW   2048               // k = i*32 + b  (i feature 0..63, b slot 0..31)
#define B1CHUNK 8192

typedef __attribute__((ext_vector_type(8))) short short8v;
typedef __attribute__((ext_vector_type(4))) float f32x4;

__device__ __forceinline__ int dmin(int a, int b) { return a < b ? a : b; }
__device__ __forceinline__ unsigned short f2bf(float f) {
    __hip_bfloat16 h = __float2bfloat16(f);
    return *(unsigned short*)&h;
}

// ---------- K1: bbT[o][i*32+b] : b<30 -> basis[b][i][o], b==30 -> sw[i][o], b==31 -> (i==0)?bias[o]:0
__global__ void k_bbt(const float* __restrict__ basis, const float* __restrict__ sw,
                      const float* __restrict__ bias, __hip_bfloat16* __restrict__ bbT) {
    int idx = blockIdx.x * blockDim.x + threadIdx.x;
    if (idx >= OUT_F * KROW) return;
    int o = idx >> 11, k = idx & (KROW - 1);
    int i = k >> 5, b = k & 31;
    float v;
    if (b < N_BAS)      v = basis[((size_t)b * IN_F + i) * OUT_F + o];
    else if (b == 30)   v = sw[(size_t)i * OUT_F + o];
    else                v = (i == 0) ? bias[o] : 0.f;
    bbT[idx] = __float2bfloat16(v);
}

// ---------- K2: coarse histogram by tgt>>8 ----------
__global__ void __launch_bounds__(256)
k_b1a(const int* __restrict__ tgt, int* __restrict__ gsum, int E) {
    __shared__ int lh[256];
    int tid = threadIdx.x;
    lh[tid] = 0;
    __syncthreads();
    for (int i = blockIdx.x * blockDim.x + tid; i < E; i += gridDim.x * blockDim.x)
        atomicAdd(&lh[tgt[i] >> 8], 1);
    __syncthreads();
    if (lh[tid]) atomicAdd(&gsum[tid], lh[tid]);
}

// ---------- K3: tiny scan of coarse buckets ----------
__global__ void k_scanB(const int* __restrict__ gsum, int* __restrict__ gexcl,
                        int* __restrict__ bcur, int* __restrict__ off, int NB, int N) {
    int l = threadIdx.x;
    int a0 = (4*l+0 < NB) ? gsum[4*l+0] : 0;
    int a1 = (4*l+1 < NB) ? gsum[4*l+1] : 0;
    int a2 = (4*l+2 < NB) ? gsum[4*l+2] : 0;
    int a3 = (4*l+3 < NB) ? gsum[4*l+3] : 0;
    int s = a0 + a1 + a2 + a3;
    int sc = s;
    for (int d = 1; d < 64; d <<= 1) {
        int o = __shfl_up(sc, d, 64);
        if (l >= d) sc += o;
    }
    int base = sc - s;
    if (4*l+0 < NB) { gexcl[4*l+0] = base;          bcur[4*l+0] = base; }
    if (4*l+1 < NB) { gexcl[4*l+1] = base+a0;       bcur[4*l+1] = base+a0; }
    if (4*l+2 < NB) { gexcl[4*l+2] = base+a0+a1;    bcur[4*l+2] = base+a0+a1; }
    if (4*l+3 < NB) { gexcl[4*l+3] = base+a0+a1+a2; bcur[4*l+3] = base+a0+a1+a2; }
    if (l == 63) { gexcl[NB] = sc; off[N] = sc; }
}

// ---------- K4: coarse bucket scatter ----------
__global__ void __launch_bounds__(1024)
k_b1(const int* __restrict__ src, const int* __restrict__ tgt, const int* __restrict__ et,
     int* __restrict__ bcur, unsigned* __restrict__ ssr, int E) {
    __shared__ unsigned ls_p[B1CHUNK];
    __shared__ unsigned char ls_b[B1CHUNK];
    __shared__ int lh[256], lbase[256], gbase[256], lcur[256];
    int tid = threadIdx.x;
    int e0 = blockIdx.x * B1CHUNK;
    int n = E - e0; if (n > B1CHUNK) n = B1CHUNK;
    if (tid < 256) { lh[tid] = 0; lcur[tid] = 0; }
    __syncthreads();
    unsigned pr[8]; int br[8];
#pragma unroll
    for (int k = 0; k < 8; ++k) {
        int i = k * 1024 + tid;
        br[k] = -1;
        if (i < n) {
            int t = tgt[e0 + i];
            br[k] = t >> 8;
            pr[k] = ((unsigned)(t & 255) << 21) | ((unsigned)src[e0 + i] << 5) | (unsigned)et[e0 + i];
            atomicAdd(&lh[br[k]], 1);
        }
    }
    __syncthreads();
    if (tid < 64) {
        int a0 = lh[4*tid], a1 = lh[4*tid+1], a2 = lh[4*tid+2], a3 = lh[4*tid+3];
        int s = a0 + a1 + a2 + a3, sc = s;
        for (int d = 1; d < 64; d <<= 1) {
            int o = __shfl_up(sc, d, 64);
            if (tid >= d) sc += o;
        }
        int base = sc - s;
        lbase[4*tid] = base; lbase[4*tid+1] = base+a0;
        lbase[4*tid+2] = base+a0+a1; lbase[4*tid+3] = base+a0+a1+a2;
    }
    __syncthreads();
    if (tid < 256 && lh[tid]) gbase[tid] = atomicAdd(&bcur[tid], lh[tid]);
    __syncthreads();
#pragma unroll
    for (int k = 0; k < 8; ++k) {
        if (br[k] >= 0) {
            int pos = atomicAdd(&lcur[br[k]], 1);
            int s = lbase[br[k]] + pos;
            ls_p[s] = pr[k];
            ls_b[s] = (unsigned char)br[k];
        }
    }
    __syncthreads();
#pragma unroll
    for (int k = 0; k < 8; ++k) {
        int i = k * 1024 + tid;
        if (i < n) {
            int b = ls_b[i];
            ssr[gbase[b] + (i - lbase[b])] = ls_p[i];
        }
    }
}

// ---------- K5: per-bucket fine sort ----------
__global__ void __launch_bounds__(256)
k_b2(const unsigned* __restrict__ ssr, const int* __restrict__ gexcl,
     int* __restrict__ off, unsigned* __restrict__ ssr2, int N) {
    __shared__ int lh[256], lofs[256], lcur[256];
    int g = blockIdx.x, tid = threadIdx.x;
    int o0 = gexcl[g], o1 = gexcl[g + 1];
    lh[tid] = 0;
    __syncthreads();
    for (int i = o0 + tid; i < o1; i += 256)
        atomicAdd(&lh[ssr[i] >> 21], 1);
    __syncthreads();
    if (tid < 64) {
        int a0 = lh[4*tid], a1 = lh[4*tid+1], a2 = lh[4*tid+2], a3 = lh[4*tid+3];
        int s = a0 + a1 + a2 + a3, sc = s;
        for (int d = 1; d < 64; d <<= 1) {
            int o = __shfl_up(sc, d, 64);
            if (tid >= d) sc += o;
        }
        int base = sc - s;
        lofs[4*tid] = base; lofs[4*tid+1] = base+a0;
        lofs[4*tid+2] = base+a0+a1; lofs[4*tid+3] = base+a0+a1+a2;
    }
    __syncthreads();
    int t = (g << 8) + tid;
    if (t < N) off[t] = o0 + lofs[tid];
    lcur[tid] = o0 + lofs[tid];
    __syncthreads();
    for (int i = o0 + tid; i < o1; i += 256) {
        unsigned p = ssr[i];
        int pos = atomicAdd(&lcur[p >> 21], 1);
        ssr2[pos] = p;
    }
}

// ---------- K6: fused v4 — deep-pipelined edge phase (u x8 in SGPR ring, x x6 in VGPR ring) ----------
__global__ void __launch_bounds__(1024, 8)
k_fused(const float* __restrict__ x, const unsigned* __restrict__ ssr2,
        const int* __restrict__ off, const float* __restrict__ coeff,
        const __hip_bfloat16* __restrict__ bbT, float* __restrict__ out, int N) {
    __shared__ __align__(16) unsigned char zb[16 * 4096];   // 16 x 2048 bf16, XOR-swizzled
    __shared__ float pf[16 * 256];                          // partials [kq*4+colblk][row][col16]
    int tid = threadIdx.x;
    int w = tid >> 6, lane = tid & 63;
    int t0 = blockIdx.x * 16;
    int t = t0 + w;

    // ---- edge phase: 1 wave = 1 target; deep software pipeline on ssr2 words + x gathers
    float yb[N_BAS];
#pragma unroll
    for (int b = 0; b < N_BAS; ++b) yb[b] = 0.f;
    float xself = 0.f;
    int deg = 0;
    if (t < N) {
        int s0 = __builtin_amdgcn_readfirstlane(off[t]);
        int s1 = __builtin_amdgcn_readfirstlane(off[t + 1]);
        deg = s1 - s0;
        xself = x[((size_t)t << 6) + lane];
        if (s1 > s0) {
            int last = s1 - 1;
            // u ring: 8 deep, wave-uniform -> SGPRs (shift = s_mov, SALU pipe)
            unsigned uq[8];
#pragma unroll
            for (int k = 0; k < 8; ++k) uq[k] = ssr2[dmin(s0 + k, last)];
            // x ring: 6 deep, per-lane gathered value (1 dword/lane, 256B/row coalesced)
            float xq[6];
#pragma unroll
            for (int k = 0; k < 6; ++k)
                xq[k] = x[((size_t)((uq[k] >> 5) & 0xFFFFu) << 6) + lane];
            for (int e = s0; e < s1; ++e) {
                int r = __builtin_amdgcn_readfirstlane((int)(uq[0] & 31u));
                const float* c = coeff + r * N_BAS;     // wave-uniform -> scalar loads
                float xa = xq[0];
#pragma unroll
                for (int b = 0; b < N_BAS; ++b) yb[b] += c[b] * xa;
                // rotate rings (fully unrolled -> static indexing)
#pragma unroll
                for (int k = 0; k < 7; ++k) uq[k] = uq[k + 1];
                uq[7] = ssr2[dmin(e + 8, last)];        // edge e+8 (post-shift slot 7)
#pragma unroll
                for (int k = 0; k < 5; ++k) xq[k] = xq[k + 1];
                // edge e+6: its u word was loaded 2 iterations ago -> s_load long arrived
                xq[5] = x[((size_t)((uq[5] >> 5) & 0xFFFFu) << 6) + lane];
            }
        }
    }
    float inv = 1.f / fmaxf((float)deg, 1.f);
    unsigned short pk[32];
#pragma unroll
    for (int b = 0; b < N_BAS; ++b) pk[b] = f2bf(yb[b] * inv);
    pk[30] = f2bf(xself);
    pk[31] = (lane == 0) ? (unsigned short)0x3F80 : (unsigned short)0;

    // LDS row write: lane owns bytes [lane*64, +64) of row w, swizzled byte^=(row&7)<<4
    {
        unsigned rb = (unsigned)w << 12;
        unsigned swz = (unsigned)((w & 7) << 4);
#pragma unroll
        for (int q = 0; q < 4; ++q) {
            unsigned byt = (((unsigned)lane << 6) + ((unsigned)q << 4)) ^ swz;
            *(short8v*)(zb + rb + byt) = *(const short8v*)(pk + q * 8);
        }
    }
    __syncthreads();

    // ---- MFMA phase: wave w -> colblk=w&3, K-quarter kq=w>>2 (512 each, 16 steps)
    int l15 = lane & 15, lk = lane >> 4;
    int colblk = w & 3, kq = w >> 2;
    const short8v* bp = (const short8v*)(bbT + (((size_t)(colblk * 16 + l15)) << 11) + (kq << 9) + lk * 8);
    unsigned arow = (unsigned)l15 << 12;
    unsigned aswz = (unsigned)((l15 & 7) << 4);
    f32x4 acc = {0.f, 0.f, 0.f, 0.f};
#pragma unroll 4
    for (int s = 0; s < 16; ++s) {
        unsigned abyte = ((unsigned)((kq << 10) + (s << 6) + (lk << 4))) ^ aswz;
        short8v a = *(const short8v*)(zb + arow + abyte);
        short8v b = bp[s * 4];
        acc = __builtin_amdgcn_mfma_f32_16x16x32_bf16(a, b, acc, 0, 0, 0);
    }
#pragma unroll
    for (int q = 0; q < 4; ++q)                      // D: col=lane&15, row=lk*4+q
        pf[(w << 8) + ((lk << 2) + q) * 16 + l15] = acc[q];
    __syncthreads();

    // ---- reduce 4 K-quarters + write (1024 threads = 1024 outputs)
    {
        int row = w, col = lane;
        int cb = col >> 4, cl = col & 15;
        int tt = t0 + row;
        if (tt < N) {
            float v = pf[((0 << 2) + cb) * 256 + row * 16 + cl]
                    + pf[((1 << 2) + cb) * 256 + row * 16 + cl]
                    + pf[((2 << 2) + cb) * 256 + row * 16 + cl]
                    + pf[((3 << 2) + cb) * 256 + row * 16 + cl];
            out[((size_t)tt << 6) + col] = v;
        }
    }
}

extern "C" void kernel_launch(void* const* d_in, const int* in_sizes, int n_in,
                              void* d_out, int out_size, void* d_ws, size_t ws_size,
                              hipStream_t stream) {
    const float* x     = (const float*)d_in[0];
    const int*   eidx  = (const int*)d_in[1];   // (2, E)
    const int*   etype = (const int*)d_in[2];
    const float* basis = (const float*)d_in[4];
    const float* coeff = (const float*)d_in[5];
    const float* sw    = (const float*)d_in[6];
    const float* bias  = (const float*)d_in[7];

    const int E = in_sizes[1] / 2;
    const int N = out_size / OUT_F;
    const int NB = (N + 255) >> 8;
    const int* srcv = eidx;
    const int* tgtv = eidx + E;
    float* out = (float*)d_out;

    size_t p = 0;
    auto alloc = [&](size_t bytes) { size_t cur = p; p += (bytes + 255) & ~(size_t)255; return cur; };
    char* base = (char*)d_ws;
    __hip_bfloat16* bbT   = (__hip_bfloat16*)(base + alloc((size_t)OUT_F * KROW * 2));
    int*            gsum  = (int*)(base + alloc(256 * 4));
    int*            gexcl = (int*)(base + alloc((size_t)(NB + 1) * 4));
    int*            bcur  = (int*)(base + alloc((size_t)NB * 4));
    int*            off   = (int*)(base + alloc((size_t)(N + 1) * 4));
    unsigned*       ssr   = (unsigned*)(base + alloc((size_t)E * 4));
    unsigned*       ssr2  = (unsigned*)(base + alloc((size_t)E * 4));
    (void)ws_size;

    hipMemsetAsync(gsum, 0, 256 * 4, stream);

    k_bbt<<<(OUT_F * KROW + 255) / 256, 256, 0, stream>>>(basis, sw, bias, bbT);
    k_b1a<<<256, 256, 0, stream>>>(tgtv, gsum, E);
    k_scanB<<<1, 64, 0, stream>>>(gsum, gexcl, bcur, off, NB, N);
    k_b1<<<(E + B1CHUNK - 1) / B1CHUNK, 1024, 0, stream>>>(srcv, tgtv, etype, bcur, ssr, E);
    k_b2<<<NB, 256, 0, stream>>>(ssr, gexcl, off, ssr2, N);
    k_fused<<<(N + 15) / 16, 1024, 0, stream>>>(x, ssr2, off, coeff, bbT, out, N);
}